// Round 19
// baseline (194.191 us; speedup 1.0000x reference)
//
#include <hip/hip_runtime.h>
#include <hip/hip_bf16.h>
#include <stdint.h>

#define N_NODES 6144
#define IN_F    512
#define OUT_F   64
#define NH      8
#define ALPHA   0.2f
#define L2E     1.4426950408889634f
#define NTILES  (N_NODES / 64)   // 96

typedef __attribute__((ext_vector_type(8))) short bf16x8;
typedef __attribute__((ext_vector_type(8))) _Float16 f16x8;
typedef __attribute__((ext_vector_type(4))) float f32x4;

#define MFMA16B(a, b, c) __builtin_amdgcn_mfma_f32_16x16x32_bf16(a, b, c, 0, 0, 0)
#define MFMA16H(a, b, c) __builtin_amdgcn_mfma_f32_16x16x32_f16(a, b, c, 0, 0, 0)

__device__ __forceinline__ unsigned short f2bf(float f) {
    uint32_t u = __float_as_uint(f);
    u += 0x7fffu + ((u >> 16) & 1u);     // round-to-nearest-even
    return (unsigned short)(u >> 16);
}
__device__ __forceinline__ float bf2f(unsigned short h) {
    return __uint_as_float(((uint32_t)h) << 16);
}
__device__ __forceinline__ unsigned short f16b(float f) {
    union { _Float16 h; unsigned short u; } c;
    c.h = (_Float16)f;
    return c.u;
}
// monotone float<->uint encoding for atomicMax on floats (any sign)
__device__ __forceinline__ uint32_t encf(float x) {
    int i = __float_as_int(x);
    return (i >= 0) ? ((uint32_t)i | 0x80000000u) : ~(uint32_t)i;
}
__device__ __forceinline__ float decf(uint32_t u) {
    int i = (u & 0x80000000u) ? (int)(u & 0x7FFFFFFFu) : ~(int)u;
    return __int_as_float(i);
}

// ---------------------------------------------------------------------------
// k_conv: [0,3072) convert_x ; [3072,3200) convert_w (fragment-order)+s2mu
__global__ __launch_bounds__(256) void k_conv(
    const float* __restrict__ x, unsigned short* __restrict__ xh,
    unsigned short* __restrict__ xl,
    const float* __restrict__ W, unsigned short* __restrict__ wthF,
    unsigned short* __restrict__ wtlF, uint32_t* __restrict__ s2mu)
{
    const int bid = blockIdx.x;
    if (bid < 3072) {
        int i = bid * 256 + threadIdx.x;             // per float4, 786432
        float4 v = ((const float4*)x)[i];
        float vv[4] = {v.x, v.y, v.z, v.w};
        unsigned short h4[4], l4[4];
#pragma unroll
        for (int c = 0; c < 4; ++c) {
            unsigned short hb = f2bf(vv[c]);
            h4[c] = hb;
            l4[c] = f2bf(vv[c] - bf2f(hb));
        }
        ((ushort4*)xh)[i] = make_ushort4(h4[0], h4[1], h4[2], h4[3]);
        ((ushort4*)xl)[i] = make_ushort4(l4[0], l4[1], l4[2], l4[3]);
    } else {
        int tid = (bid - 3072) * 256 + threadIdx.x;  // 32768
        if (bid == 3072 && threadIdx.x < NH) s2mu[threadIdx.x] = 0u;
        int lane = tid & 63;
        int rest = tid >> 6;
        int ct = rest & 3;
        int i = (rest >> 2) & 15;
        int h = rest >> 6;
        int f = ct * 16 + (lane & 15);
        int k0 = i * 32 + (lane >> 4) * 8;
        unsigned short oh[8], ol[8];
#pragma unroll
        for (int e = 0; e < 8; ++e) {
            float wv = W[((size_t)h * IN_F + k0 + e) * OUT_F + f];
            unsigned short hb = f2bf(wv);
            oh[e] = hb;
            ol[e] = f2bf(wv - bf2f(hb));
        }
        ushort4* dh = (ushort4*)(wthF + (size_t)tid * 8);
        dh[0] = make_ushort4(oh[0], oh[1], oh[2], oh[3]);
        dh[1] = make_ushort4(oh[4], oh[5], oh[6], oh[7]);
        ushort4* dl = (ushort4*)(wtlF + (size_t)tid * 8);
        dl[0] = make_ushort4(ol[0], ol[1], ol[2], ol[3]);
        dl[1] = make_ushort4(ol[4], ol[5], ol[6], ol[7]);
    }
}

// ---------------------------------------------------------------------------
// k_projpack: fused pack_adj (HBM-bound) + proj (MFMA/L2-bound).
//   [0,2304)    : pack_adj — ROW-MAJOR bitmask writes: bmRM[r][cb]. The old
//                 transposed store (bmT[cb*6144+r]) scattered every 8B write
//                 at 49KB stride = one DRAM page-open per store (~590k) —
//                 THE invariant ~107us across all R10-R18 read-side variants.
//                 Row-major makes a wave's writes land in one page.
//   [2304,3072) : proj — h=x@W, s1/s2, s2max, hTF fragments (head = bid&7)
__global__ __launch_bounds__(256) void k_projpack(
    const unsigned short* __restrict__ xh, const unsigned short* __restrict__ xl,
    const unsigned short* __restrict__ wthF, const unsigned short* __restrict__ wtlF,
    const float* __restrict__ a1, const float* __restrict__ a2,
    float* __restrict__ s1, float* __restrict__ s2,
    uint32_t* __restrict__ s2mu, unsigned short* __restrict__ hTF,
    const int* __restrict__ adj, unsigned long long* __restrict__ bmRM)
{
    __shared__ unsigned short hlds[64][64];          // 8 KB (proj only)

    const int bid = blockIdx.x;
    if (bid < 2304) {
        // ---- pack_adj: int4 stream, butterfly OR, row-major writes ----
        const int tid = threadIdx.x;
        const int lane = tid & 63;
        const int lg = lane & 15;                    // nibble slot in word
        const int wg = lane >> 4;                    // which word of 4
        const int wid = bid * 4 + (tid >> 6);        // 0..9215
        uint32_t q = (uint32_t)wid * 16u;            // 1KB-load index
        const int4* ap = (const int4*)adj + (size_t)q * 64 + lane;
#pragma unroll 4
        for (int it = 0; it < 16; ++it, ++q) {
            int4 v = ap[(size_t)it * 64];
            uint32_t nib = (v.x > 0 ? 1u : 0u) | (v.y > 0 ? 2u : 0u) |
                           (v.z > 0 ? 4u : 0u) | (v.w > 0 ? 8u : 0u);
            uint32_t lo = (lg < 8) ? (nib << (4 * lg)) : 0u;
            uint32_t hi = (lg < 8) ? 0u : (nib << (4 * (lg - 8)));
#pragma unroll
            for (int d = 1; d < 16; d <<= 1) {       // OR within 16-lane grp
                lo |= __shfl_xor(lo, d);
                hi |= __shfl_xor(hi, d);
            }
            if (lg == 0) {
                uint32_t r = q / 24u;                // row
                uint32_t cb = (q % 24u) * 4u + (uint32_t)wg;
                bmRM[(size_t)r * 96 + cb] =          // row-major: page-local
                    ((unsigned long long)hi << 32) | lo;
            }
        }
        return;
    }

    // ---- proj ----
    const int pb = bid - 2304;                       // 0..767
    const int head = pb & 7;
    const int rb = pb >> 3;                          // 0..95
    const int w = threadIdx.x >> 6;
    const int lane = threadIdx.x & 63;
    const int r15 = lane & 15;
    const int g = lane >> 4;
    const int rowbase = rb * 64 + w * 16;
    const int rowA = rowbase + r15;

    f32x4 acc[4] = {};
    const unsigned short* xhp = xh + (size_t)rowA * IN_F + g * 8;
    const unsigned short* xlp = xl + (size_t)rowA * IN_F + g * 8;
    const unsigned short* wb = wthF + ((size_t)head * 16 * 4 * 64) * 8 + lane * 8;
    const unsigned short* wl = wtlF + ((size_t)head * 16 * 4 * 64) * 8 + lane * 8;

#pragma unroll 4
    for (int i = 0; i < 16; ++i) {
        const int k0 = i * 32;
        bf16x8 ah = *(const bf16x8*)(xhp + k0);
        bf16x8 al = *(const bf16x8*)(xlp + k0);
#pragma unroll
        for (int ct = 0; ct < 4; ++ct) {
            const size_t fo = (size_t)(i * 4 + ct) * 512;
            bf16x8 bh = *(const bf16x8*)(wb + fo);
            bf16x8 bl = *(const bf16x8*)(wl + fo);
            acc[ct] = MFMA16B(ah, bh, acc[ct]);
            acc[ct] = MFMA16B(ah, bl, acc[ct]);
            acc[ct] = MFMA16B(al, bh, acc[ct]);
        }
    }

    float a1v[4], a2v[4];
#pragma unroll
    for (int ct = 0; ct < 4; ++ct) {
        a1v[ct] = a1[head * 64 + ct * 16 + r15];
        a2v[ct] = a2[head * 64 + ct * 16 + r15];
    }
    float sp1[4] = {0, 0, 0, 0}, sp2[4] = {0, 0, 0, 0};
#pragma unroll
    for (int ct = 0; ct < 4; ++ct)
#pragma unroll
        for (int j = 0; j < 4; ++j) {
            sp1[j] += acc[ct][j] * a1v[ct];
            sp2[j] += acc[ct][j] * a2v[ct];
        }
#pragma unroll
    for (int d = 1; d < 16; d <<= 1) {
#pragma unroll
        for (int j = 0; j < 4; ++j) {
            sp1[j] += __shfl_xor(sp1[j], d);
            sp2[j] += __shfl_xor(sp2[j], d);
        }
    }
    if (r15 == 0) {
#pragma unroll
        for (int j = 0; j < 4; ++j) {
            int n = rowbase + g * 4 + j;
            s1[head * N_NODES + n] = sp1[j];
            s2[head * N_NODES + n] = sp2[j];
        }
    }
    {   // per-head s2 max: wave-reduce then one atomic
        float m = fmaxf(fmaxf(sp2[0], sp2[1]), fmaxf(sp2[2], sp2[3]));
        m = fmaxf(m, __shfl_xor(m, 16));
        m = fmaxf(m, __shfl_xor(m, 32));
        if (lane == 0) atomicMax(s2mu + head, encf(m));
    }

    // ---- stage f16 tile to LDS (chunk-XOR swizzle) ----
#pragma unroll
    for (int ct = 0; ct < 4; ++ct) {
        ushort4 pk;
        pk.x = f16b(acc[ct][0]);
        pk.y = f16b(acc[ct][1]);
        pk.z = f16b(acc[ct][2]);
        pk.w = f16b(acc[ct][3]);
        int f_l = ct * 16 + r15;
        int n0 = w * 16 + g * 4;
        int col = (((n0 >> 3) ^ (f_l & 7)) << 3) + (n0 & 7);
        *(ushort4*)&hlds[f_l][col] = pk;
    }
    __syncthreads();

    // ---- write MFMA-B fragments (f16) to hTF, coalesced ----
#pragma unroll
    for (int q = 0; q < 2; ++q) {
        int fid = 2 * w + q;                          // 0..7 = wk*4+ct
        int wk = fid >> 2, ct = fid & 3;
        int f_l = ct * 16 + (lane & 15);
        int nch = wk * 4 + (lane >> 4);
        int col = ((nch ^ (f_l & 7)) << 3);
        int4 v = *(const int4*)&hlds[f_l][col];
        size_t base = (((size_t)(head * 96 + rb)) * 8 + fid) * 512 + lane * 8;
        *(int4*)(hTF + base) = v;
    }
}

// ---------------------------------------------------------------------------
// packed-f16 P fragment: p2 = max(E1p2*ep2, E1n2*en2), mask via bfe + bfi
__device__ __forceinline__ f16x8 mk_pa16(int4 ep, int4 en, uint32_t e1p2,
                                         uint32_t e1n2, uint32_t ms,
                                         uint32_t kFFFF)
{
    const uint32_t epw[4] = {(uint32_t)ep.x, (uint32_t)ep.y, (uint32_t)ep.z,
                             (uint32_t)ep.w};
    const uint32_t enw[4] = {(uint32_t)en.x, (uint32_t)en.y, (uint32_t)en.z,
                             (uint32_t)en.w};
    union { uint32_t u[4]; f16x8 v; } r;
#define PAIR(J, B0, B1)                                                       \
    {                                                                         \
        uint32_t pa, pb, pm, mw;                                              \
        asm("v_pk_mul_f16 %0, %1, %2" : "=v"(pa) : "v"(e1p2), "v"(epw[J]));   \
        asm("v_pk_mul_f16 %0, %1, %2" : "=v"(pb) : "v"(e1n2), "v"(enw[J]));   \
        asm("v_pk_max_f16 %0, %1, %2" : "=v"(pm) : "v"(pa), "v"(pb));         \
        uint32_t mb0, mb1;                                                    \
        asm("v_bfe_i32 %0, %1, " #B0 ", 1" : "=v"(mb0) : "v"(ms));            \
        asm("v_bfe_i32 %0, %1, " #B1 ", 1" : "=v"(mb1) : "v"(ms));            \
        asm("v_bfi_b32 %0, %1, %2, %3"                                        \
            : "=v"(mw) : "s"(kFFFF), "v"(mb0), "v"(mb1));                     \
        r.u[J] = pm & mw;                                                     \
    }
    PAIR(0, 0, 1)
    PAIR(1, 2, 3)
    PAIR(2, 4, 5)
    PAIR(3, 6, 7)
#undef PAIR
    return r.v;
}

struct Ph {                          // hb rotation slot (3-deep, L2-latency)
    int4 hb0, hb1, hb2, hb3;         // 4 H B-fragments (f16, this wave's kk)
};
struct Pm {                          // mask rotation slot (6-deep)
    uint32_t m0, m1;                 // adjacency mask words per row-group
};

__device__ __forceinline__ f16x8 as_f16x8(int4 v) {
    union { int4 i; f16x8 h; } c;
    c.i = v;
    return c.h;
}

// ---------------------------------------------------------------------------
// Flash attention: barrier-free; head = bid&7; LDS ep/en tables; split-depth
// pinned prefetch (hb 3-deep, masks 6-deep), vmcnt(14)/phase; setprio.
// Masks now read from ROW-MAJOR bmRM: two pointers (rA, rB rows), each
// advancing +8 B per tile (contiguous 768 B per row — better locality).
__global__ __launch_bounds__(256, 3) void k_flash(
    const unsigned short* __restrict__ hTF, const float* __restrict__ s1,
    const float* __restrict__ s2, const uint32_t* __restrict__ s2mu,
    const uint32_t* __restrict__ bmRM32, float* __restrict__ out)
{
    __shared__ uint32_t epL[3072];                   // 12 KB packed-f16 tables
    __shared__ uint32_t enL[3072];                   // 12 KB
    __shared__ float fs[128 * 20];                   // 10 KB epilogue scratch

    const int head = blockIdx.x & 7;                 // == XCD id (round-robin)
    const int rb = blockIdx.x >> 3;
    const int tid = threadIdx.x;
    const int w = tid >> 6, lane = tid & 63, r15 = lane & 15, g = lane >> 4;
    const int w01 = w & 1;                           // row half
    const int wk = w >> 1;                           // m half (kk)
    const int shg = g * 8;                           // mask bit offset
    const uint32_t kFFFF = 0xFFFFu;

    // ---- prologue: build packed-f16 ep/en tables for this head in LDS ----
    const float s2mh = decf(s2mu[head]);
    {
        const float4* s2h = (const float4*)(s2 + head * N_NODES);
#pragma unroll
        for (int i0 = 0; i0 < 6; ++i0) {
            int i = tid + i0 * 256;                  // 1536 float4s
            float4 v = s2h[i];
            uint32_t p0 = f16b(exp2f((v.x - s2mh) * L2E));
            uint32_t p1 = f16b(exp2f((v.y - s2mh) * L2E));
            uint32_t p2 = f16b(exp2f((v.z - s2mh) * L2E));
            uint32_t p3 = f16b(exp2f((v.w - s2mh) * L2E));
            uint32_t n0 = f16b(exp2f(ALPHA * (v.x - s2mh) * L2E));
            uint32_t n1 = f16b(exp2f(ALPHA * (v.y - s2mh) * L2E));
            uint32_t n2 = f16b(exp2f(ALPHA * (v.z - s2mh) * L2E));
            uint32_t n3 = f16b(exp2f(ALPHA * (v.w - s2mh) * L2E));
            epL[2 * i] = p0 | (p1 << 16);
            epL[2 * i + 1] = p2 | (p3 << 16);
            enL[2 * i] = n0 | (n1 << 16);
            enL[2 * i + 1] = n2 | (n3 << 16);
        }
    }

    const int rA = rb * 64 + w01 * 32 + r15;
    const int rB = rA + 16;
    const float s1A = s1[head * N_NODES + rA];
    const float s1B = s1[head * N_NODES + rB];
    const float t0A = s1A + s2mh, t0B = s1B + s2mh;
    const float MrA = fmaxf(t0A, ALPHA * t0A);
    const float MrB = fmaxf(t0B, ALPHA * t0B);
    uint32_t E1pA2, E1nA2, E1pB2, E1nB2;
    {
        uint32_t a = f16b(exp2f((t0A - MrA) * L2E));
        uint32_t b = f16b(exp2f((ALPHA * t0A - MrA) * L2E));
        uint32_t c = f16b(exp2f((t0B - MrB) * L2E));
        uint32_t d = f16b(exp2f((ALPHA * t0B - MrB) * L2E));
        E1pA2 = a | (a << 16);
        E1nA2 = b | (b << 16);
        E1pB2 = c | (c << 16);
        E1nB2 = d | (d << 16);
    }

    // incrementing 64-bit vaddr pointers
    const unsigned short* hp = hTF +
        ((size_t)(head * 96) * 8 + wk * 4) * 512 + lane * 8;
    const uint32_t* pa = bmRM32 + (size_t)rA * 192 + wk;  // row-major masks
    const uint32_t* pb = bmRM32 + (size_t)rB * 192 + wk;

    const uint32_t* __restrict__ epb = epL + wk * 16 + g * 4;
    const uint32_t* __restrict__ enb = enL + wk * 16 + g * 4;

    f32x4 accA[4] = {}, accB[4] = {};
    f32x4 accSA = {}, accSB = {};
    const f16x8 vones = {(_Float16)1.0f, (_Float16)1.0f, (_Float16)1.0f,
                         (_Float16)1.0f, (_Float16)1.0f, (_Float16)1.0f,
                         (_Float16)1.0f, (_Float16)1.0f};

    __syncthreads();                                 // tables ready

    auto loadH = [&](Ph& P) {
        asm volatile("global_load_dwordx4 %0, %1, off"
                     : "=v"(P.hb0) : "v"(hp));
        asm volatile("global_load_dwordx4 %0, %1, off offset:1024"
                     : "=v"(P.hb1) : "v"(hp));
        asm volatile("global_load_dwordx4 %0, %1, off offset:2048"
                     : "=v"(P.hb2) : "v"(hp));
        asm volatile("global_load_dwordx4 %0, %1, off offset:3072"
                     : "=v"(P.hb3) : "v"(hp));
        hp += 4096;                                  // 8 KB / tile
    };
    auto loadM = [&](Pm& P) {
        asm volatile("global_load_dword %0, %1, off"
                     : "=v"(P.m0) : "v"(pa));
        asm volatile("global_load_dword %0, %1, off"
                     : "=v"(P.m1) : "v"(pb));
        pa += 2;                                     // 8 B / tile (row-major)
        pb += 2;
    };
    auto compute = [&](int t, Ph& H, Pm& M) {
        int4 ep = *(const int4*)(epb + t * 32);      // LDS broadcast reads
        int4 en = *(const int4*)(enb + t * 32);
        f16x8 paA = mk_pa16(ep, en, E1pA2, E1nA2, M.m0 >> shg, kFFFF);
        f16x8 paB = mk_pa16(ep, en, E1pB2, E1nB2, M.m1 >> shg, kFFFF);
        __builtin_amdgcn_s_setprio(1);
        accSA = MFMA16H(paA, vones, accSA);
        accSB = MFMA16H(paB, vones, accSB);
        f16x8 h0 = as_f16x8(H.hb0), h1 = as_f16x8(H.hb1);
        f16x8 h2 = as_f16x8(H.hb2), h3 = as_f16x8(H.hb3);
        accA[0] = MFMA16H(paA, h0, accA[0]);
        accB[0] = MFMA16H(paB, h0, accB[0]);
        accA[1] = MFMA16H(paA, h1, accA[1]);
        accB[1] = MFMA16H(paB, h1, accB[1]);
        accA[2] = MFMA16H(paA, h2, accA[2]);
        accB[2] = MFMA16H(paB, h2, accB[2]);
        accA[3] = MFMA16H(paA, h3, accA[3]);
        accB[3] = MFMA16H(paB, h3, accB[3]);
        __builtin_amdgcn_s_setprio(0);
    };

    Ph H0, H1, H2;
    Pm M0, M1, M2, M3, M4, M5;
    // prologue queue: m0,m1,m2 | h0,m3 | h1,m4 | h2,m5  (24 loads out)
    loadM(M0);
    loadM(M1);
    loadM(M2);
    loadH(H0);
    loadM(M3);
    loadH(H1);
    loadM(M4);
    loadH(H2);
    loadM(M5);

#define PHASE(K, HH, MM)                                                      \
    asm volatile("s_waitcnt vmcnt(14)");                                      \
    __builtin_amdgcn_sched_barrier(0);                                        \
    compute(t + K, HH, MM);                                                   \
    loadH(HH);                                                                \
    loadM(MM);

    for (int t = 0; t < NTILES; t += 6) {
        PHASE(0, H0, M0)
        PHASE(1, H1, M1)
        PHASE(2, H2, M2)
        PHASE(3, H0, M3)
        PHASE(4, H1, M4)
        PHASE(5, H2, M5)
    }
#undef PHASE
    // drain: in-flight tail loads still target H/M registers
    asm volatile("s_waitcnt vmcnt(0)");
    __builtin_amdgcn_sched_barrier(0);

    // ---- epilogue: combine the two m-half waves through LDS ----
    const int slot = w01 * 64 + lane;
    const int fcb = head * 64;
    const int nA = rb * 64 + w01 * 32 + g * 4;

    if (wk == 1) {
#pragma unroll
        for (int ct = 0; ct < 4; ++ct)
#pragma unroll
            for (int j = 0; j < 4; ++j) fs[slot * 20 + ct * 4 + j] = accA[ct][j];
#pragma unroll
        for (int j = 0; j < 4; ++j) fs[slot * 20 + 16 + j] = accSA[j];
    }
    __syncthreads();
    if (wk == 0) {
        float rinv[4];
#pragma unroll
        for (int j = 0; j < 4; ++j)
            rinv[j] = 1.0f / (accSA[j] + fs[slot * 20 + 16 + j]);
#pragma unroll
        for (int ct = 0; ct < 4; ++ct)
#pragma unroll
            for (int j = 0; j < 4; ++j) {
                float v = (accA[ct][j] + fs[slot * 20 + ct * 4 + j]) * rinv[j];
                v = (v > 0.f) ? v : (expf(v) - 1.f);
                out[(size_t)(nA + j) * 512 + fcb + ct * 16 + r15] = v;
            }
    }
    __syncthreads();
    if (wk == 1) {
#pragma unroll
        for (int ct = 0; ct < 4; ++ct)
#pragma unroll
            for (int j = 0; j < 4; ++j) fs[slot * 20 + ct * 4 + j] = accB[ct][j];
#pragma unroll
        for (int j = 0; j < 4; ++j) fs[slot * 20 + 16 + j] = accSB[j];
    }
    __syncthreads();
    if (wk == 0) {
        float rinv[4];
#pragma unroll
        for (int j = 0; j < 4; ++j)
            rinv[j] = 1.0f / (accSB[j] + fs[slot * 20 + 16 + j]);
#pragma unroll
        for (int ct = 0; ct < 4; ++ct)
#pragma unroll
            for (int j = 0; j < 4; ++j) {
                float v = (accB[ct][j] + fs[slot * 20 + ct * 4 + j]) * rinv[j];
                v = (v > 0.f) ? v : (expf(v) - 1.f);
                out[(size_t)(nA + 16 + j) * 512 + fcb + ct * 16 + r15] = v;
            }
    }
}

// ---------------------------------------------------------------------------
extern "C" void kernel_launch(void* const* d_in, const int* in_sizes, int n_in,
                              void* d_out, int out_size, void* d_ws, size_t ws_size,
                              hipStream_t stream)
{
    const float* x = (const float*)d_in[0];
    const int* adj = (const int*)d_in[1];
    const float* W = (const float*)d_in[2];
    const float* a1 = (const float*)d_in[3];
    const float* a2 = (const float*)d_in[4];
    float* out = (float*)d_out;

    char* ws = (char*)d_ws;
    size_t off = 0;
    auto take = [&](size_t bytes) {
        void* p = ws + off;
        off = (off + bytes + 255) & ~(size_t)255;
        return p;
    };
    unsigned short* xh   = (unsigned short*)take((size_t)N_NODES * IN_F * 2);
    unsigned short* xl   = (unsigned short*)take((size_t)N_NODES * IN_F * 2);
    unsigned short* wthF = (unsigned short*)take((size_t)512 * 512 * 2);
    unsigned short* wtlF = (unsigned short*)take((size_t)512 * 512 * 2);
    // +32 KB slack: flash prefetches hb up to tile 98 (drained, unused)
    unsigned short* hTF  = (unsigned short*)take(
        (size_t)NH * 64 * N_NODES * 2 + 32768);
    float* s1  = (float*)take((size_t)NH * N_NODES * 4);
    float* s2  = (float*)take((size_t)NH * N_NODES * 4);
    uint32_t* s2mu = (uint32_t*)take(256);
    // +384 KB slack: mask prefetch overruns the last rows (drained, unused)
    unsigned long long* bmRM = (unsigned long long*)take(
        (size_t)N_NODES * (N_NODES / 64) * 8 + 393216);

    k_conv<<<dim3(3200), dim3(256), 0, stream>>>(
        x, xh, xl, W, wthF, wtlF, s2mu);
    k_projpack<<<dim3(3072), dim3(256), 0, stream>>>(
        xh, xl, wthF, wtlF, a1, a2, s1, s2, s2mu, hTF, adj, bmRM);
    k_flash<<<dim3(NH * NTILES), dim3(256), 0, stream>>>(
        hTF, s1, s2, s2mu, (const uint32_t*)bmRM, out);
}

// Round 20
// 142.037 us; speedup vs baseline: 1.3672x; 1.3672x over previous
//
#include <hip/hip_runtime.h>
#include <hip/hip_bf16.h>
#include <stdint.h>

#define N_NODES 6144
#define IN_F    512
#define OUT_F   64
#define NH      8
#define ALPHA   0.2f
#define L2E     1.4426950408889634f
#define NTILES  (N_NODES / 64)   // 96

typedef __attribute__((ext_vector_type(8))) short bf16x8;
typedef __attribute__((ext_vector_type(8))) _Float16 f16x8;
typedef __attribute__((ext_vector_type(4))) float f32x4;

#define MFMA16B(a, b, c) __builtin_amdgcn_mfma_f32_16x16x32_bf16(a, b, c, 0, 0, 0)
#define MFMA16H(a, b, c) __builtin_amdgcn_mfma_f32_16x16x32_f16(a, b, c, 0, 0, 0)

__device__ __forceinline__ unsigned short f2bf(float f) {
    uint32_t u = __float_as_uint(f);
    u += 0x7fffu + ((u >> 16) & 1u);     // round-to-nearest-even
    return (unsigned short)(u >> 16);
}
__device__ __forceinline__ float bf2f(unsigned short h) {
    return __uint_as_float(((uint32_t)h) << 16);
}
__device__ __forceinline__ unsigned short f16b(float f) {
    union { _Float16 h; unsigned short u; } c;
    c.h = (_Float16)f;
    return c.u;
}
// monotone float<->uint encoding for atomicMax on floats (any sign)
__device__ __forceinline__ uint32_t encf(float x) {
    int i = __float_as_int(x);
    return (i >= 0) ? ((uint32_t)i | 0x80000000u) : ~(uint32_t)i;
}
__device__ __forceinline__ float decf(uint32_t u) {
    int i = (u & 0x80000000u) ? (int)(u & 0x7FFFFFFFu) : ~(int)u;
    return __int_as_float(i);
}

// ---------------------------------------------------------------------------
// k_conv: [0,3072) convert_x ; [3072,3200) convert_w (fragment-order)+s2mu
__global__ __launch_bounds__(256) void k_conv(
    const float* __restrict__ x, unsigned short* __restrict__ xh,
    unsigned short* __restrict__ xl,
    const float* __restrict__ W, unsigned short* __restrict__ wthF,
    unsigned short* __restrict__ wtlF, uint32_t* __restrict__ s2mu)
{
    const int bid = blockIdx.x;
    if (bid < 3072) {
        int i = bid * 256 + threadIdx.x;             // per float4, 786432
        float4 v = ((const float4*)x)[i];
        float vv[4] = {v.x, v.y, v.z, v.w};
        unsigned short h4[4], l4[4];
#pragma unroll
        for (int c = 0; c < 4; ++c) {
            unsigned short hb = f2bf(vv[c]);
            h4[c] = hb;
            l4[c] = f2bf(vv[c] - bf2f(hb));
        }
        ((ushort4*)xh)[i] = make_ushort4(h4[0], h4[1], h4[2], h4[3]);
        ((ushort4*)xl)[i] = make_ushort4(l4[0], l4[1], l4[2], l4[3]);
    } else {
        int tid = (bid - 3072) * 256 + threadIdx.x;  // 32768
        if (bid == 3072 && threadIdx.x < NH) s2mu[threadIdx.x] = 0u;
        int lane = tid & 63;
        int rest = tid >> 6;
        int ct = rest & 3;
        int i = (rest >> 2) & 15;
        int h = rest >> 6;
        int f = ct * 16 + (lane & 15);
        int k0 = i * 32 + (lane >> 4) * 8;
        unsigned short oh[8], ol[8];
#pragma unroll
        for (int e = 0; e < 8; ++e) {
            float wv = W[((size_t)h * IN_F + k0 + e) * OUT_F + f];
            unsigned short hb = f2bf(wv);
            oh[e] = hb;
            ol[e] = f2bf(wv - bf2f(hb));
        }
        ushort4* dh = (ushort4*)(wthF + (size_t)tid * 8);
        dh[0] = make_ushort4(oh[0], oh[1], oh[2], oh[3]);
        dh[1] = make_ushort4(oh[4], oh[5], oh[6], oh[7]);
        ushort4* dl = (ushort4*)(wtlF + (size_t)tid * 8);
        dl[0] = make_ushort4(ol[0], ol[1], ol[2], ol[3]);
        dl[1] = make_ushort4(ol[4], ol[5], ol[6], ol[7]);
    }
}

// ---------------------------------------------------------------------------
// k_projpack: fused pack_adj (HBM-bound) + proj (MFMA/L2-bound).
//   [0,384)   : pack_adj — BOTH-SIDES-COALESCED via LDS transpose:
//               sequential int4 reads (R18 pattern) -> nibble/butterfly ->
//               LDS bmL[16][97] -> TRANSPOSED writes in 128B contiguous
//               segments. (R10-16: coalesced writes/strided reads = 107us;
//               R17-18: sequential reads/49KB-scatter writes = 107us;
//               R19 proved write-locality is the other half.)
//   [384,1152): proj — h=x@W, s1/s2, s2max, hTF fragments (head = pb&7)
__global__ __launch_bounds__(256) void k_projpack(
    const unsigned short* __restrict__ xh, const unsigned short* __restrict__ xl,
    const unsigned short* __restrict__ wthF, const unsigned short* __restrict__ wtlF,
    const float* __restrict__ a1, const float* __restrict__ a2,
    float* __restrict__ s1, float* __restrict__ s2,
    uint32_t* __restrict__ s2mu, unsigned short* __restrict__ hTF,
    const int* __restrict__ adj, unsigned long long* __restrict__ bmT)
{
    __shared__ unsigned short hlds[64][64];          // 8 KB (proj only)
    __shared__ unsigned long long bmL[16][97];       // 12.4 KB (pack only)

    const int bid = blockIdx.x;
    const int tid = threadIdx.x;
    if (bid < 384) {
        // ---- pack_adj: 16 rows per block, 4 rows per wave ----
        const int lane = tid & 63;
        const int w = tid >> 6;
        const int lg = lane & 15;                    // nibble slot in word
        const int wg = lane >> 4;                    // which word of 4
        const int rbase = bid * 16;
        const int4* ap[4];
#pragma unroll
        for (int rr = 0; rr < 4; ++rr)
            ap[rr] = (const int4*)adj +
                     (size_t)(rbase + w * 4 + rr) * 1536 + lane;
#pragma unroll 2
        for (int it = 0; it < 24; ++it) {
            int4 v0 = ap[0][(size_t)it * 64];
            int4 v1 = ap[1][(size_t)it * 64];
            int4 v2 = ap[2][(size_t)it * 64];
            int4 v3 = ap[3][(size_t)it * 64];
#pragma unroll
            for (int rr = 0; rr < 4; ++rr) {
                int4 v = (rr == 0) ? v0 : (rr == 1) ? v1 : (rr == 2) ? v2 : v3;
                uint32_t nib = (v.x > 0 ? 1u : 0u) | (v.y > 0 ? 2u : 0u) |
                               (v.z > 0 ? 4u : 0u) | (v.w > 0 ? 8u : 0u);
                uint32_t lo = (lg < 8) ? (nib << (4 * lg)) : 0u;
                uint32_t hi = (lg < 8) ? 0u : (nib << (4 * (lg - 8)));
#pragma unroll
                for (int d = 1; d < 16; d <<= 1) {   // OR within 16-lane grp
                    lo |= __shfl_xor(lo, d);
                    hi |= __shfl_xor(hi, d);
                }
                if (lg == 0)
                    bmL[w * 4 + rr][it * 4 + wg] =
                        ((unsigned long long)hi << 32) | lo;
            }
        }
        __syncthreads();
        // transposed write-out: 128 B contiguous per cb segment
#pragma unroll
        for (int iter = 0; iter < 6; ++iter) {
            int cb = iter * 16 + (tid >> 4);
            int r = tid & 15;
            bmT[(size_t)cb * N_NODES + rbase + r] = bmL[r][cb];
        }
        return;
    }

    // ---- proj ----
    const int pb = bid - 384;                        // 0..767
    const int head = pb & 7;
    const int rb = pb >> 3;                          // 0..95
    const int w = tid >> 6;
    const int lane = tid & 63;
    const int r15 = lane & 15;
    const int g = lane >> 4;
    const int rowbase = rb * 64 + w * 16;
    const int rowA = rowbase + r15;

    f32x4 acc[4] = {};
    const unsigned short* xhp = xh + (size_t)rowA * IN_F + g * 8;
    const unsigned short* xlp = xl + (size_t)rowA * IN_F + g * 8;
    const unsigned short* wb = wthF + ((size_t)head * 16 * 4 * 64) * 8 + lane * 8;
    const unsigned short* wl = wtlF + ((size_t)head * 16 * 4 * 64) * 8 + lane * 8;

#pragma unroll 4
    for (int i = 0; i < 16; ++i) {
        const int k0 = i * 32;
        bf16x8 ah = *(const bf16x8*)(xhp + k0);
        bf16x8 al = *(const bf16x8*)(xlp + k0);
#pragma unroll
        for (int ct = 0; ct < 4; ++ct) {
            const size_t fo = (size_t)(i * 4 + ct) * 512;
            bf16x8 bh = *(const bf16x8*)(wb + fo);
            bf16x8 bl = *(const bf16x8*)(wl + fo);
            acc[ct] = MFMA16B(ah, bh, acc[ct]);
            acc[ct] = MFMA16B(ah, bl, acc[ct]);
            acc[ct] = MFMA16B(al, bh, acc[ct]);
        }
    }

    float a1v[4], a2v[4];
#pragma unroll
    for (int ct = 0; ct < 4; ++ct) {
        a1v[ct] = a1[head * 64 + ct * 16 + r15];
        a2v[ct] = a2[head * 64 + ct * 16 + r15];
    }
    float sp1[4] = {0, 0, 0, 0}, sp2[4] = {0, 0, 0, 0};
#pragma unroll
    for (int ct = 0; ct < 4; ++ct)
#pragma unroll
        for (int j = 0; j < 4; ++j) {
            sp1[j] += acc[ct][j] * a1v[ct];
            sp2[j] += acc[ct][j] * a2v[ct];
        }
#pragma unroll
    for (int d = 1; d < 16; d <<= 1) {
#pragma unroll
        for (int j = 0; j < 4; ++j) {
            sp1[j] += __shfl_xor(sp1[j], d);
            sp2[j] += __shfl_xor(sp2[j], d);
        }
    }
    if (r15 == 0) {
#pragma unroll
        for (int j = 0; j < 4; ++j) {
            int n = rowbase + g * 4 + j;
            s1[head * N_NODES + n] = sp1[j];
            s2[head * N_NODES + n] = sp2[j];
        }
    }
    {   // per-head s2 max: wave-reduce then one atomic
        float m = fmaxf(fmaxf(sp2[0], sp2[1]), fmaxf(sp2[2], sp2[3]));
        m = fmaxf(m, __shfl_xor(m, 16));
        m = fmaxf(m, __shfl_xor(m, 32));
        if (lane == 0) atomicMax(s2mu + head, encf(m));
    }

    // ---- stage f16 tile to LDS (chunk-XOR swizzle) ----
#pragma unroll
    for (int ct = 0; ct < 4; ++ct) {
        ushort4 pk;
        pk.x = f16b(acc[ct][0]);
        pk.y = f16b(acc[ct][1]);
        pk.z = f16b(acc[ct][2]);
        pk.w = f16b(acc[ct][3]);
        int f_l = ct * 16 + r15;
        int n0 = w * 16 + g * 4;
        int col = (((n0 >> 3) ^ (f_l & 7)) << 3) + (n0 & 7);
        *(ushort4*)&hlds[f_l][col] = pk;
    }
    __syncthreads();

    // ---- write MFMA-B fragments (f16) to hTF, coalesced ----
#pragma unroll
    for (int q = 0; q < 2; ++q) {
        int fid = 2 * w + q;                          // 0..7 = wk*4+ct
        int wk = fid >> 2, ct = fid & 3;
        int f_l = ct * 16 + (lane & 15);
        int nch = wk * 4 + (lane >> 4);
        int col = ((nch ^ (f_l & 7)) << 3);
        int4 v = *(const int4*)&hlds[f_l][col];
        size_t base = (((size_t)(head * 96 + rb)) * 8 + fid) * 512 + lane * 8;
        *(int4*)(hTF + base) = v;
    }
}

// ---------------------------------------------------------------------------
// packed-f16 P fragment: p2 = max(E1p2*ep2, E1n2*en2), mask via bfe + bfi
__device__ __forceinline__ f16x8 mk_pa16(int4 ep, int4 en, uint32_t e1p2,
                                         uint32_t e1n2, uint32_t ms,
                                         uint32_t kFFFF)
{
    const uint32_t epw[4] = {(uint32_t)ep.x, (uint32_t)ep.y, (uint32_t)ep.z,
                             (uint32_t)ep.w};
    const uint32_t enw[4] = {(uint32_t)en.x, (uint32_t)en.y, (uint32_t)en.z,
                             (uint32_t)en.w};
    union { uint32_t u[4]; f16x8 v; } r;
#define PAIR(J, B0, B1)                                                       \
    {                                                                         \
        uint32_t pa, pb, pm, mw;                                              \
        asm("v_pk_mul_f16 %0, %1, %2" : "=v"(pa) : "v"(e1p2), "v"(epw[J]));   \
        asm("v_pk_mul_f16 %0, %1, %2" : "=v"(pb) : "v"(e1n2), "v"(enw[J]));   \
        asm("v_pk_max_f16 %0, %1, %2" : "=v"(pm) : "v"(pa), "v"(pb));         \
        uint32_t mb0, mb1;                                                    \
        asm("v_bfe_i32 %0, %1, " #B0 ", 1" : "=v"(mb0) : "v"(ms));            \
        asm("v_bfe_i32 %0, %1, " #B1 ", 1" : "=v"(mb1) : "v"(ms));            \
        asm("v_bfi_b32 %0, %1, %2, %3"                                        \
            : "=v"(mw) : "s"(kFFFF), "v"(mb0), "v"(mb1));                     \
        r.u[J] = pm & mw;                                                     \
    }
    PAIR(0, 0, 1)
    PAIR(1, 2, 3)
    PAIR(2, 4, 5)
    PAIR(3, 6, 7)
#undef PAIR
    return r.v;
}

struct Ph {                          // hb rotation slot (3-deep, L2-latency)
    int4 hb0, hb1, hb2, hb3;         // 4 H B-fragments (f16, this wave's kk)
};
struct Pm {                          // mask rotation slot (6-deep)
    uint32_t m0, m1;                 // adjacency mask words per row-group
};

__device__ __forceinline__ f16x8 as_f16x8(int4 v) {
    union { int4 i; f16x8 h; } c;
    c.i = v;
    return c.h;
}

// ---------------------------------------------------------------------------
// Flash attention (R13/R18 version, verbatim): barrier-free; head = bid&7;
// LDS ep/en tables; split-depth pinned prefetch (hb 3-deep, masks 6-deep)
// from TRANSPOSED bmT (coalesced per-tile mask loads); vmcnt(14)/phase.
__global__ __launch_bounds__(256, 3) void k_flash(
    const unsigned short* __restrict__ hTF, const float* __restrict__ s1,
    const float* __restrict__ s2, const uint32_t* __restrict__ s2mu,
    const uint32_t* __restrict__ bmT32, float* __restrict__ out)
{
    __shared__ uint32_t epL[3072];                   // 12 KB packed-f16 tables
    __shared__ uint32_t enL[3072];                   // 12 KB
    __shared__ float fs[128 * 20];                   // 10 KB epilogue scratch

    const int head = blockIdx.x & 7;                 // == XCD id (round-robin)
    const int rb = blockIdx.x >> 3;
    const int tid = threadIdx.x;
    const int w = tid >> 6, lane = tid & 63, r15 = lane & 15, g = lane >> 4;
    const int w01 = w & 1;                           // row half
    const int wk = w >> 1;                           // m half (kk)
    const int shg = g * 8;                           // mask bit offset
    const uint32_t kFFFF = 0xFFFFu;

    // ---- prologue: build packed-f16 ep/en tables for this head in LDS ----
    const float s2mh = decf(s2mu[head]);
    {
        const float4* s2h = (const float4*)(s2 + head * N_NODES);
#pragma unroll
        for (int i0 = 0; i0 < 6; ++i0) {
            int i = tid + i0 * 256;                  // 1536 float4s
            float4 v = s2h[i];
            uint32_t p0 = f16b(exp2f((v.x - s2mh) * L2E));
            uint32_t p1 = f16b(exp2f((v.y - s2mh) * L2E));
            uint32_t p2 = f16b(exp2f((v.z - s2mh) * L2E));
            uint32_t p3 = f16b(exp2f((v.w - s2mh) * L2E));
            uint32_t n0 = f16b(exp2f(ALPHA * (v.x - s2mh) * L2E));
            uint32_t n1 = f16b(exp2f(ALPHA * (v.y - s2mh) * L2E));
            uint32_t n2 = f16b(exp2f(ALPHA * (v.z - s2mh) * L2E));
            uint32_t n3 = f16b(exp2f(ALPHA * (v.w - s2mh) * L2E));
            epL[2 * i] = p0 | (p1 << 16);
            epL[2 * i + 1] = p2 | (p3 << 16);
            enL[2 * i] = n0 | (n1 << 16);
            enL[2 * i + 1] = n2 | (n3 << 16);
        }
    }

    const int rA = rb * 64 + w01 * 32 + r15;
    const int rB = rA + 16;
    const float s1A = s1[head * N_NODES + rA];
    const float s1B = s1[head * N_NODES + rB];
    const float t0A = s1A + s2mh, t0B = s1B + s2mh;
    const float MrA = fmaxf(t0A, ALPHA * t0A);
    const float MrB = fmaxf(t0B, ALPHA * t0B);
    uint32_t E1pA2, E1nA2, E1pB2, E1nB2;
    {
        uint32_t a = f16b(exp2f((t0A - MrA) * L2E));
        uint32_t b = f16b(exp2f((ALPHA * t0A - MrA) * L2E));
        uint32_t c = f16b(exp2f((t0B - MrB) * L2E));
        uint32_t d = f16b(exp2f((ALPHA * t0B - MrB) * L2E));
        E1pA2 = a | (a << 16);
        E1nA2 = b | (b << 16);
        E1pB2 = c | (c << 16);
        E1nB2 = d | (d << 16);
    }

    // incrementing 64-bit vaddr pointers
    const unsigned short* hp = hTF +
        ((size_t)(head * 96) * 8 + wk * 4) * 512 + lane * 8;
    const uint32_t* pa = bmT32 + (size_t)rA * 2 + wk;   // rB mask at +128 B

    const uint32_t* __restrict__ epb = epL + wk * 16 + g * 4;
    const uint32_t* __restrict__ enb = enL + wk * 16 + g * 4;

    f32x4 accA[4] = {}, accB[4] = {};
    f32x4 accSA = {}, accSB = {};
    const f16x8 vones = {(_Float16)1.0f, (_Float16)1.0f, (_Float16)1.0f,
                         (_Float16)1.0f, (_Float16)1.0f, (_Float16)1.0f,
                         (_Float16)1.0f, (_Float16)1.0f};

    __syncthreads();                                 // tables ready

    auto loadH = [&](Ph& P) {
        asm volatile("global_load_dwordx4 %0, %1, off"
                     : "=v"(P.hb0) : "v"(hp));
        asm volatile("global_load_dwordx4 %0, %1, off offset:1024"
                     : "=v"(P.hb1) : "v"(hp));
        asm volatile("global_load_dwordx4 %0, %1, off offset:2048"
                     : "=v"(P.hb2) : "v"(hp));
        asm volatile("global_load_dwordx4 %0, %1, off offset:3072"
                     : "=v"(P.hb3) : "v"(hp));
        hp += 4096;                                  // 8 KB / tile
    };
    auto loadM = [&](Pm& P) {
        asm volatile("global_load_dword %0, %1, off"
                     : "=v"(P.m0) : "v"(pa));
        asm volatile("global_load_dword %0, %1, off offset:128"
                     : "=v"(P.m1) : "v"(pa));
        pa += 12288;                                 // 48 KB / tile
    };
    auto compute = [&](int t, Ph& H, Pm& M) {
        int4 ep = *(const int4*)(epb + t * 32);      // LDS broadcast reads
        int4 en = *(const int4*)(enb + t * 32);
        f16x8 paA = mk_pa16(ep, en, E1pA2, E1nA2, M.m0 >> shg, kFFFF);
        f16x8 paB = mk_pa16(ep, en, E1pB2, E1nB2, M.m1 >> shg, kFFFF);
        __builtin_amdgcn_s_setprio(1);
        accSA = MFMA16H(paA, vones, accSA);
        accSB = MFMA16H(paB, vones, accSB);
        f16x8 h0 = as_f16x8(H.hb0), h1 = as_f16x8(H.hb1);
        f16x8 h2 = as_f16x8(H.hb2), h3 = as_f16x8(H.hb3);
        accA[0] = MFMA16H(paA, h0, accA[0]);
        accB[0] = MFMA16H(paB, h0, accB[0]);
        accA[1] = MFMA16H(paA, h1, accA[1]);
        accB[1] = MFMA16H(paB, h1, accB[1]);
        accA[2] = MFMA16H(paA, h2, accA[2]);
        accB[2] = MFMA16H(paB, h2, accB[2]);
        accA[3] = MFMA16H(paA, h3, accA[3]);
        accB[3] = MFMA16H(paB, h3, accB[3]);
        __builtin_amdgcn_s_setprio(0);
    };

    Ph H0, H1, H2;
    Pm M0, M1, M2, M3, M4, M5;
    // prologue queue: m0,m1,m2 | h0,m3 | h1,m4 | h2,m5  (24 loads out)
    loadM(M0);
    loadM(M1);
    loadM(M2);
    loadH(H0);
    loadM(M3);
    loadH(H1);
    loadM(M4);
    loadH(H2);
    loadM(M5);

#define PHASE(K, HH, MM)                                                      \
    asm volatile("s_waitcnt vmcnt(14)");                                      \
    __builtin_amdgcn_sched_barrier(0);                                        \
    compute(t + K, HH, MM);                                                   \
    loadH(HH);                                                                \
    loadM(MM);

    for (int t = 0; t < NTILES; t += 6) {
        PHASE(0, H0, M0)
        PHASE(1, H1, M1)
        PHASE(2, H2, M2)
        PHASE(3, H0, M3)
        PHASE(4, H1, M4)
        PHASE(5, H2, M5)
    }
#undef PHASE
    // drain: in-flight tail loads still target H/M registers
    asm volatile("s_waitcnt vmcnt(0)");
    __builtin_amdgcn_sched_barrier(0);

    // ---- epilogue: combine the two m-half waves through LDS ----
    const int slot = w01 * 64 + lane;
    const int fcb = head * 64;
    const int nA = rb * 64 + w01 * 32 + g * 4;

    if (wk == 1) {
#pragma unroll
        for (int ct = 0; ct < 4; ++ct)
#pragma unroll
            for (int j = 0; j < 4; ++j) fs[slot * 20 + ct * 4 + j] = accA[ct][j];
#pragma unroll
        for (int j = 0; j < 4; ++j) fs[slot * 20 + 16 + j] = accSA[j];
    }
    __syncthreads();
    if (wk == 0) {
        float rinv[4];
#pragma unroll
        for (int j = 0; j < 4; ++j)
            rinv[j] = 1.0f / (accSA[j] + fs[slot * 20 + 16 + j]);
#pragma unroll
        for (int ct = 0; ct < 4; ++ct)
#pragma unroll
            for (int j = 0; j < 4; ++j) {
                float v = (accA[ct][j] + fs[slot * 20 + ct * 4 + j]) * rinv[j];
                v = (v > 0.f) ? v : (expf(v) - 1.f);
                out[(size_t)(nA + j) * 512 + fcb + ct * 16 + r15] = v;
            }
    }
    __syncthreads();
    if (wk == 1) {
#pragma unroll
        for (int ct = 0; ct < 4; ++ct)
#pragma unroll
            for (int j = 0; j < 4; ++j) fs[slot * 20 + ct * 4 + j] = accB[ct][j];
#pragma unroll
        for (int j = 0; j < 4; ++j) fs[slot * 20 + 16 + j] = accSB[j];
    }
    __syncthreads();
    if (wk == 0) {
        float rinv[4];
#pragma unroll
        for (int j = 0; j < 4; ++j)
            rinv[j] = 1.0f / (accSB[j] + fs[slot * 20 + 16 + j]);
#pragma unroll
        for (int ct = 0; ct < 4; ++ct)
#pragma unroll
            for (int j = 0; j < 4; ++j) {
                float v = (accB[ct][j] + fs[slot * 20 + ct * 4 + j]) * rinv[j];
                v = (v > 0.f) ? v : (expf(v) - 1.f);
                out[(size_t)(nA + 16 + j) * 512 + fcb + ct * 16 + r15] = v;
            }
    }
}

// ---------------------------------------------------------------------------
extern "C" void kernel_launch(void* const* d_in, const int* in_sizes, int n_in,
                              void* d_out, int out_size, void* d_ws, size_t ws_size,
                              hipStream_t stream)
{
    const float* x = (const float*)d_in[0];
    const int* adj = (const int*)d_in[1];
    const float* W = (const float*)d_in[2];
    const float* a1 = (const float*)d_in[3];
    const float* a2 = (const float*)d_in[4];
    float* out = (float*)d_out;

    char* ws = (char*)d_ws;
    size_t off = 0;
    auto take = [&](size_t bytes) {
        void* p = ws + off;
        off = (off + bytes + 255) & ~(size_t)255;
        return p;
    };
    unsigned short* xh   = (unsigned short*)take((size_t)N_NODES * IN_F * 2);
    unsigned short* xl   = (unsigned short*)take((size_t)N_NODES * IN_F * 2);
    unsigned short* wthF = (unsigned short*)take((size_t)512 * 512 * 2);
    unsigned short* wtlF = (unsigned short*)take((size_t)512 * 512 * 2);
    // +32 KB slack: flash prefetches hb up to tile 98 (drained, unused)
    unsigned short* hTF  = (unsigned short*)take(
        (size_t)NH * 64 * N_NODES * 2 + 32768);
    float* s1  = (float*)take((size_t)NH * N_NODES * 4);
    float* s2  = (float*)take((size_t)NH * N_NODES * 4);
    uint32_t* s2mu = (uint32_t*)take(256);
    // +384 KB slack: mask prefetch reaches tile 101 (drained, unused)
    unsigned long long* bmT = (unsigned long long*)take(
        (size_t)N_NODES * (N_NODES / 64) * 8 + 393216);

    k_conv<<<dim3(3200), dim3(256), 0, stream>>>(
        x, xh, xl, W, wthF, wtlF, s2mu);
    k_projpack<<<dim3(1152), dim3(256), 0, stream>>>(
        xh, xl, wthF, wtlF, a1, a2, s1, s2, s2mu, hTF, adj, bmT);
    k_flash<<<dim3(NH * NTILES), dim3(256), 0, stream>>>(
        hTF, s1, s2, s2mu, (const uint32_t*)bmT, out);
}